// Round 1
// baseline (468.518 us; speedup 1.0000x reference)
//
#include <hip/hip_runtime.h>

#define NPTS   21
#define BATCH  16384
#define ROWS   (BATCH * NPTS)            // 344064 flat (b*21+n) rows
#define NGRP   ((BATCH + 2) / 3)         // 5462 groups of 3 batch elems (63 rows -> pad 64)
#define GPB    2                         // groups per block
#define NBLK   ((NGRP + GPB - 1) / GPB)  // 2731 blocks
#define ZSTR   392                       // LDS row stride in u16 (384+8 pad; 784B = 49*16B, banks 196%32=4)

typedef unsigned short u16;
typedef unsigned int   u32;
typedef __bf16 bf16x8 __attribute__((ext_vector_type(8)));
typedef u16    u16x8  __attribute__((ext_vector_type(8)));
typedef float  f32x4  __attribute__((ext_vector_type(4)));

static __device__ __forceinline__ u16 f2bf(float f) {
  union { float f; u32 u; } v; v.f = f;
  u32 r = v.u + 0x7fffu + ((v.u >> 16) & 1u);   // RNE
  return (u16)(r >> 16);
}
static __device__ __forceinline__ float bf2f(u16 u) {
  union { u32 u; float f; } v; v.u = ((u32)u) << 16;
  return v.f;
}

// ---- prep: T1/T2 Chebyshev matrices + transposed bf16 weights --------------
__global__ void cheb_prep(const float* __restrict__ adj,
                          const float* __restrict__ weight,   // [3][1][128][128]
                          float* __restrict__ TG,             // [2][21][21]
                          u16*  __restrict__ WtG) {           // [128][384]: Wt[d][k*128+c]
  const int tid = threadIdx.x;
  const int gid = blockIdx.x * 256 + tid;
  for (int idx = gid; idx < 128 * 384; idx += 64 * 256) {
    int d  = idx / 384;
    int kc = idx - d * 384;                    // kc = k*128 + c
    WtG[idx] = f2bf(weight[kc * 128 + d]);     // weight[(k*128+c)*128 + d]
  }
  if (blockIdx.x == 0) {
    __shared__ float Ls[NPTS * NPTS];
    __shared__ float dsi[NPTS];
    if (tid < NPTS) {
      float s = 0.f;
      for (int m = 0; m < NPTS; ++m) s += adj[tid * NPTS + m];
      dsi[tid] = (s > 0.f) ? (1.0f / sqrtf(s)) : 0.f;
    }
    __syncthreads();
    for (int i = tid; i < NPTS * NPTS; i += 256) {
      int n = i / NPTS, m = i - n * NPTS;
      float l = ((n == m) ? 1.f : 0.f) - dsi[n] * adj[i] * dsi[m];
      Ls[i] = l;
      TG[i] = l;                               // T1 = L
    }
    __syncthreads();
    for (int i = tid; i < NPTS * NPTS; i += 256) {
      int n = i / NPTS, m = i - n * NPTS;
      float s = 0.f;
      for (int j = 0; j < NPTS; ++j) s += Ls[n * NPTS + j] * Ls[j * NPTS + m];
      TG[NPTS * NPTS + i] = 2.f * s - ((n == m) ? 1.f : 0.f);  // T2 = 2L^2 - I
    }
  }
}

// ---- main: fused stage -> mix -> MFMA GEMM ---------------------------------
__global__ void __launch_bounds__(256, 3) cheb_main(
    const float* __restrict__ x,      // [16384][21][128] fp32
    const u16*  __restrict__ WtG,     // [128][384] bf16 bits
    const float* __restrict__ TG,     // [2][21][21] (uniform -> scalar loads)
    const float* __restrict__ bias,   // [128]
    float* __restrict__ out) {        // [16384][21][128] fp32
  __shared__ u16 zb[64 * ZSTR];       // Z tile: 64 rows x 384 (k,c) cols, bf16

  const int tid  = threadIdx.x;
  const int wave = tid >> 6;
  const int lane = tid & 63;
  const int quad = lane >> 4;
  const int l15  = lane & 15;

  // persistent B fragments: wave owns output cols [wave*32, wave*32+31]
  // B[k'=quad*8+j][n=l15] -> Wt[n][k'] contiguous 8 u16
  u16x8 Breg[2][12];
  const int c0 = wave * 32 + l15;
  const int c1 = wave * 32 + 16 + l15;
#pragma unroll
  for (int t = 0; t < 2; ++t) {
    const u16* wp = WtG + (wave * 32 + t * 16 + l15) * 384 + quad * 8;
#pragma unroll
    for (int s = 0; s < 12; ++s) Breg[t][s] = *(const u16x8*)(wp + s * 32);
  }
  const float bias0 = bias[c0];
  const float bias1 = bias[c1];

  // pad-row 63 k1/k2 slots: zero once (staging re-zeros its k0 slot each iter)
  if (tid < 32) *(uint4*)(&zb[63 * ZSTR + 128 + tid * 8]) = make_uint4(0u, 0u, 0u, 0u);

  for (int it = 0; it < GPB; ++it) {
    const int grp = blockIdx.x * GPB + it;
    if (grp >= NGRP) break;                    // uniform across block
    const int gr0 = grp * 63;                  // first flat row of this group

    __syncthreads();                           // prev group's MFMA reads done
    // ---- stage x -> zb[:, 0:128] as bf16 (zeros for pad/OOB) ----
#pragma unroll
    for (int i = 0; i < 8; ++i) {
      int task = i * 256 + tid;                // 64 rows x 32 float4 chunks
      int r = task >> 5, q = task & 31;
      int gr = gr0 + r;
      float4 v = make_float4(0.f, 0.f, 0.f, 0.f);
      if (r < 63 && gr < ROWS) v = *(const float4*)(x + (size_t)gr * 128 + q * 4);
      u32 lo = (u32)f2bf(v.x) | ((u32)f2bf(v.y) << 16);
      u32 hi = (u32)f2bf(v.z) | ((u32)f2bf(v.w) << 16);
      *(uint2*)(&zb[r * ZSTR + q * 4]) = make_uint2(lo, hi);
    }
    __syncthreads();

    // ---- mixing: zb[:, 128:256] = T1 x, zb[:, 256:384] = T2 x ----
    for (int t = tid; t < 3 * 128; t += 256) {
      int lb = t >> 7;                         // local batch elem 0..2
      int c  = t & 127;
      float xm[NPTS];
#pragma unroll
      for (int m = 0; m < NPTS; ++m) xm[m] = bf2f(zb[(lb * NPTS + m) * ZSTR + c]);
#pragma unroll
      for (int k = 0; k < 2; ++k) {
#pragma unroll
        for (int n = 0; n < NPTS; ++n) {
          float s = 0.f;
#pragma unroll
          for (int m = 0; m < NPTS; ++m)
            s += TG[(k * NPTS + n) * NPTS + m] * xm[m];  // uniform -> s_load
          zb[(lb * NPTS + n) * ZSTR + (k + 1) * 128 + c] = f2bf(s);
        }
      }
    }
    __syncthreads();

    // ---- GEMM: 64 rows x this wave's 32 cols, K = 384 ----
#pragma unroll
    for (int mt = 0; mt < 4; ++mt) {
      f32x4 acc0 = {0.f, 0.f, 0.f, 0.f};
      f32x4 acc1 = {0.f, 0.f, 0.f, 0.f};
      const u16* zrow = zb + (mt * 16 + l15) * ZSTR + quad * 8;
#pragma unroll
      for (int s = 0; s < 12; ++s) {
        bf16x8 a = __builtin_bit_cast(bf16x8, *(const u16x8*)(zrow + s * 32));
        acc0 = __builtin_amdgcn_mfma_f32_16x16x32_bf16(
            a, __builtin_bit_cast(bf16x8, Breg[0][s]), acc0, 0, 0, 0);
        acc1 = __builtin_amdgcn_mfma_f32_16x16x32_bf16(
            a, __builtin_bit_cast(bf16x8, Breg[1][s]), acc1, 0, 0, 0);
      }
      const int rbase = mt * 16 + quad * 4;    // D: row=quad*4+reg, col=l15
#pragma unroll
      for (int i = 0; i < 4; ++i) {
        int r = rbase + i;
        int gr = gr0 + r;
        if (r < 63 && gr < ROWS) {
          float* op = out + (size_t)gr * 128;
          op[c0] = acc0[i] + bias0;
          op[c1] = acc1[i] + bias1;
        }
      }
    }
  }
}

extern "C" void kernel_launch(void* const* d_in, const int* in_sizes, int n_in,
                              void* d_out, int out_size, void* d_ws, size_t ws_size,
                              hipStream_t stream) {
  (void)in_sizes; (void)n_in; (void)out_size; (void)ws_size;
  const float* x      = (const float*)d_in[0];
  const float* adj    = (const float*)d_in[1];
  const float* weight = (const float*)d_in[2];
  const float* bias   = (const float*)d_in[3];
  float* out = (float*)d_out;
  float* TG  = (float*)d_ws;                    // 882 floats (3.5 KB)
  u16*   WtG = (u16*)((char*)d_ws + 4096);      // 49152 u16 (96 KB)
  cheb_prep<<<64, 256, 0, stream>>>(adj, weight, TG, WtG);
  cheb_main<<<NBLK, 256, 0, stream>>>(x, WtG, TG, bias, out);
}